// Round 3
// baseline (150.236 us; speedup 1.0000x reference)
//
#include <hip/hip_runtime.h>
#include <hip/hip_bf16.h>
#include <hip/hip_fp16.h>

// Problem constants
#define NNv   40
#define MMv   40
#define OOv   200
#define KKv   1600
#define OPAD  208             // 13 col-tiles of 16
#define NSTEPS 50             // KK / 32
#define CHUNK_BYTES 13312     // OPAD * 4 slots * 16 B (one K=32 chunk of W-fp16)
#define XSTR  44              // fp32 per x row in LDS (bank-quad permutation)
#define YSTR  40              // fp16 per y row in LDS (stride 20 dw: perfect partition)

typedef _Float16 half8  __attribute__((ext_vector_type(8)));
typedef _Float16 half2v __attribute__((ext_vector_type(2)));
typedef __attribute__((ext_vector_type(4))) float floatx4;

// ---------------------------------------------------------------------------
// Pre-kernel: W [200][1600] fp32 -> Wh fp16, K-chunk-major, 16B-slot swizzled.
// element idx = c*6656 + slot*8 + j ; slot = o*4 + (kg ^ ((o>>1)&3)) ;
// k = c*32 + kg*8 + j ; o in [0,208), zero-padded past 200.
// ---------------------------------------------------------------------------
__global__ void wb_convert_kernel(const float* __restrict__ W,
                                  unsigned short* __restrict__ Wh) {
    int idx = blockIdx.x * 256 + threadIdx.x;
    if (idx >= NSTEPS * OPAD * 32) return;     // 332800
    int j    = idx & 7;
    int slot = (idx >> 3) % (OPAD * 4);
    int c    = (idx >> 3) / (OPAD * 4);
    int o    = slot >> 2;
    int kgs  = slot & 3;
    int kg   = kgs ^ ((o >> 1) & 3);
    int k    = c * 32 + kg * 8 + j;
    float v  = (o < OOv) ? W[o * KKv + k] : 0.0f;
    _Float16 h = (_Float16)v;
    union { _Float16 h; unsigned short u; } cv; cv.h = h;
    Wh[idx] = cv.u;
}

// Async global->LDS stage of one 13312B W chunk (13 x 1KB units over 4 waves).
__device__ __forceinline__ void stageB(const unsigned short* __restrict__ Wh,
                                       int step, unsigned char* dst,
                                       int wave, int lane) {
    const char* src = (const char*)Wh + (size_t)step * CHUNK_BYTES;
    for (int c = wave; c < 13; c += 4) {
        int off = c * 1024 + lane * 16;
        __builtin_amdgcn_global_load_lds(
            (const __attribute__((address_space(1))) unsigned int*)(src + off),
            (__attribute__((address_space(3))) unsigned int*)(dst + off),
            16, 0, 0);
    }
}

// ---------------------------------------------------------------------------
// Main kernel: 1024 blocks x 256 threads, 64 rows x 208 cols per block.
// Wave w handles ALL 64 rows (rt=4) x col-group w: ct counts {4,3,3,3}.
// acc <= 64 AGPR, launch_bounds(256,3) -> 3 blocks/CU = 12 waves/CU.
// K-loop: 10 groups x 5-step unroll (k advances 160 = 4*40 per group, so
// y-offsets and x-index deltas are loop-invariant per slot).
// ---------------------------------------------------------------------------
__global__ __launch_bounds__(256, 3) void cin_mfma_kernel(
        const float* __restrict__ X, const float* __restrict__ Y,
        const unsigned short* __restrict__ Wh, float* __restrict__ Out) {
    __shared__ __align__(16) unsigned char bsm[2 * CHUNK_BYTES];   // 26624
    __shared__ __align__(16) float    xlds[64 * XSTR];             // 11264
    __shared__ __align__(16) _Float16 ylds[64 * YSTR];             //  5120

    const int tid  = threadIdx.x;
    const int wave = tid >> 6;
    const int lane = tid & 63;
    const int li   = lane & 15;
    const int kg   = lane >> 4;

    static const int ctbase_t[4] = {0, 4, 7, 10};
    const int cb      = ctbase_t[wave];
    const int ntiles  = (wave == 0) ? 4 : 3;
    const int obase   = cb * 16;
    const long blockbase = (long)blockIdx.x * 64;

    // ---- prologue: stage x (fp32) and y (fp16) tiles, 64 rows x 40 each
    const float* xg = X + blockbase * NNv;
    const float* yg = Y + blockbase * MMv;
    for (int i = tid; i < 640; i += 256) {       // 640 float4s = 2560 floats
        int r  = i / 10;
        int c4 = (i % 10) * 4;                   // 40 % 4 == 0: row-aligned
        floatx4 vx = *(const floatx4*)(xg + i * 4);
        *(floatx4*)(xlds + r * XSTR + c4) = vx;
        floatx4 vy = *(const floatx4*)(yg + i * 4);
        union { half2v h2[2]; unsigned long long u; } pk;
        pk.h2[0] = (half2v){(_Float16)vy.x, (_Float16)vy.y};
        pk.h2[1] = (half2v){(_Float16)vy.z, (_Float16)vy.w};
        *(unsigned long long*)(ylds + r * YSTR + c4) = pk.u;
    }
    stageB(Wh, 0, bsm, wave, lane);
    __syncthreads();

    floatx4 acc[4][4];
#pragma unroll
    for (int rt = 0; rt < 4; ++rt)
#pragma unroll
        for (int ct = 0; ct < 4; ++ct)
            acc[rt][ct] = (floatx4){0.f, 0.f, 0.f, 0.f};

    // per-lane loop-invariant y start offsets: s_j = (kg*8 + 32j) mod 40
    int soff[5];
#pragma unroll
    for (int j = 0; j < 5; ++j) soff[j] = (kg * 8 + 32 * j) % 40;

    // per-lane byte offset of frag (ct=cb) within a chunk (swizzled slots)
    const int bfoff = (obase + li) * 64 + ((kg ^ ((li >> 1) & 3)) * 16);

    for (int g = 0; g < 10; ++g) {
        unsigned char* pA = bsm + ((g & 1) ? CHUNK_BYTES : 0);  // buf for even j
        unsigned char* pB = bsm + ((g & 1) ? 0 : CHUNK_BYTES);  // buf for odd j
        const int n0 = g * 4;

        // x values for this group: 4 per rt, converted to duplicated half2
        half2v xh[4][4];
#pragma unroll
        for (int rt = 0; rt < 4; ++rt) {
            floatx4 xq = *(const floatx4*)(xlds + (li + rt * 16) * XSTR + n0);
            xh[rt][0] = (half2v){(_Float16)xq.x, (_Float16)xq.x};
            xh[rt][1] = (half2v){(_Float16)xq.y, (_Float16)xq.y};
            xh[rt][2] = (half2v){(_Float16)xq.z, (_Float16)xq.z};
            xh[rt][3] = (half2v){(_Float16)xq.w, (_Float16)xq.w};
        }

#pragma unroll
        for (int j = 0; j < 5; ++j) {
            const int step = g * 5 + j;
            unsigned char* cur = (j & 1) ? pB : pA;
            unsigned char* nxt = (j & 1) ? pA : pB;
            if (step + 1 < NSTEPS) stageB(Wh, step + 1, nxt, wave, lane);

            // B fragments: one ds_read_b128 per col-tile
            half8 bf[4];
#pragma unroll
            for (int ct = 0; ct < 4; ++ct)
                if (ct < ntiles)
                    bf[ct] = *(const half8*)(cur + bfoff + ct * 1024);

            // A fragments: xsel * y[s..s+7] via 4 v_pk_mul_f16 each
            half8 af[4];
#pragma unroll
            for (int rt = 0; rt < 4; ++rt) {
                half2v xs;
                if      (j == 0) xs = xh[rt][0];
                else if (j == 1) xs = (kg == 0) ? xh[rt][0] : xh[rt][1];
                else if (j == 2) xs = (kg < 2)  ? xh[rt][1] : xh[rt][2];
                else if (j == 3) xs = (kg == 3) ? xh[rt][3] : xh[rt][2];
                else             xs = xh[rt][3];
                half8 xsp = __builtin_shufflevector(xs, xs, 0,1,0,1,0,1,0,1);
                half8 yv = *(const half8*)(ylds + (li + rt * 16) * YSTR + soff[j]);
                af[rt] = xsp * yv;
            }

#pragma unroll
            for (int ct = 0; ct < 4; ++ct)
                if (ct < ntiles)
#pragma unroll
                    for (int rt = 0; rt < 4; ++rt)
                        acc[rt][ct] = __builtin_amdgcn_mfma_f32_16x16x32_f16(
                            af[rt], bf[ct], acc[rt][ct], 0, 0, 0);

            __syncthreads();   // drain staging (vmcnt) + finish cur reads
        }
    }

    // ---- epilogue: C/D layout col = lane&15, row = (lane>>4)*4 + reg  [m89]
#pragma unroll
    for (int rt = 0; rt < 4; ++rt) {
#pragma unroll
        for (int ct = 0; ct < 4; ++ct) {
            if (ct >= ntiles) continue;
            int gcol = obase + ct * 16 + li;
            if (gcol < OOv) {
#pragma unroll
                for (int r4 = 0; r4 < 4; ++r4) {
                    long grow = blockbase + rt * 16 + kg * 4 + r4;
                    Out[grow * OOv + gcol] = acc[rt][ct][r4];
                }
            }
        }
    }
}

extern "C" void kernel_launch(void* const* d_in, const int* in_sizes, int n_in,
                              void* d_out, int out_size, void* d_ws, size_t ws_size,
                              hipStream_t stream) {
    (void)in_sizes; (void)n_in; (void)out_size; (void)ws_size;
    const float* X = (const float*)d_in[0];
    const float* Y = (const float*)d_in[1];
    const float* W = (const float*)d_in[2];
    float* Out = (float*)d_out;
    unsigned short* Wh = (unsigned short*)d_ws;   // 665,600 B scratch

    wb_convert_kernel<<<1300, 256, 0, stream>>>(W, Wh);
    cin_mfma_kernel<<<1024, 256, 0, stream>>>(X, Y, Wh, Out);
}

// Round 4
// 122.121 us; speedup vs baseline: 1.2302x; 1.2302x over previous
//
#include <hip/hip_runtime.h>
#include <hip/hip_fp16.h>

// Problem constants
#define OOv   200
#define KKv   1600
#define OPAD  208             // 13 col-tiles of 16
#define NSTEPS 50             // K=32 steps
#define NSUPER 25             // BK=64 super-steps
#define CHUNK_BYTES 13312     // one K=32 chunk of W-fp16 (208*4 slots * 16B)
#define SUPER_BYTES 26624     // two chunks
#define XSTR 40               // halfs per x row (80 B, mult of 16)
#define YSTR 56               // halfs per y row (112 B, mult of 16; 28-dw stride = 2-way banks, free)

typedef _Float16 half8  __attribute__((ext_vector_type(8)));
typedef _Float16 half2v __attribute__((ext_vector_type(2)));
typedef __attribute__((ext_vector_type(4))) float floatx4;

// ---------------------------------------------------------------------------
// Pre-kernel: W [200][1600] fp32 -> Wh fp16, K-chunk-major, 16B-slot swizzled.
// idx = c*6656 + slot*8 + j ; slot = o*4 + (kg ^ ((o>>1)&3)) ; k = c*32+kg*8+j
// ---------------------------------------------------------------------------
__global__ void wb_convert_kernel(const float* __restrict__ W,
                                  unsigned short* __restrict__ Wh) {
    int idx = blockIdx.x * 256 + threadIdx.x;
    if (idx >= NSTEPS * OPAD * 32) return;     // 332800
    int j    = idx & 7;
    int slot = (idx >> 3) % (OPAD * 4);
    int c    = (idx >> 3) / (OPAD * 4);
    int o    = slot >> 2;
    int kgs  = slot & 3;
    int kg   = kgs ^ ((o >> 1) & 3);
    int k    = c * 32 + kg * 8 + j;
    float v  = (o < OOv) ? W[o * KKv + k] : 0.0f;
    union { _Float16 h; unsigned short u; } cv; cv.h = (_Float16)v;
    Wh[idx] = cv.u;
}

// ---------------------------------------------------------------------------
// Main kernel: 512 blocks x 256 thr, 128 rows x 208 cols per block.
// Waves: rowhalf = wave&1 (64 rows, rt=4), colgrp = wave>>1 (7/6 col-tiles).
// K-loop: 5 groups x 5 super-steps x 2 k-steps; all LDS offsets static per
// phase (period-10 pattern of k mod 40); one barrier per super-step (25).
// ---------------------------------------------------------------------------
__global__ __launch_bounds__(256, 2) void cin_mfma_kernel(
        const float* __restrict__ X, const float* __restrict__ Y,
        const unsigned short* __restrict__ Wh, float* __restrict__ Out) {
    __shared__ __align__(16) unsigned char bsm[2 * SUPER_BYTES];   // 53248
    __shared__ __align__(16) _Float16 xlds[128 * XSTR];            // 10240
    __shared__ __align__(16) _Float16 ylds[128 * YSTR];            // 14336

    const int tid     = threadIdx.x;
    const int wave    = tid >> 6;
    const int lane    = tid & 63;
    const int li      = lane & 15;
    const int kg      = lane >> 4;
    const int rowhalf = wave & 1;
    const int colgrp  = wave >> 1;
    const int ntiles  = colgrp ? 6 : 7;
    const int obase   = colgrp * 112;
    const long blockbase = (long)blockIdx.x * 128;

    // ---- prologue: stage x,y (128 rows x 40) as fp16
    const float* xg = X + blockbase * 40;
    const float* yg = Y + blockbase * 40;
    for (int i = tid; i < 1280; i += 256) {
        int r  = i / 10;
        int c4 = (i % 10) * 4;                 // 40 % 4 == 0: row-aligned
        floatx4 vx = *(const floatx4*)(xg + i * 4);
        floatx4 vy = *(const floatx4*)(yg + i * 4);
        union { half2v h[2]; unsigned long long u; } px, py;
        px.h[0] = (half2v){(_Float16)vx.x, (_Float16)vx.y};
        px.h[1] = (half2v){(_Float16)vx.z, (_Float16)vx.w};
        py.h[0] = (half2v){(_Float16)vy.x, (_Float16)vy.y};
        py.h[1] = (half2v){(_Float16)vy.z, (_Float16)vy.w};
        *(unsigned long long*)(xlds + r * XSTR + c4) = px.u;
        *(unsigned long long*)(ylds + r * YSTR + c4) = py.u;
    }
    // stage super-chunk 0 into bsm[0]
    {
        const char* src = (const char*)Wh;
        for (int c = wave; c < 26; c += 4) {
            int off = c * 1024 + lane * 16;
            __builtin_amdgcn_global_load_lds(
                (const __attribute__((address_space(1))) unsigned int*)(src + off),
                (__attribute__((address_space(3))) unsigned int*)(bsm + off),
                16, 0, 0);
        }
    }
    __syncthreads();

    floatx4 acc[4][7];
#pragma unroll
    for (int rt = 0; rt < 4; ++rt)
#pragma unroll
        for (int ct = 0; ct < 7; ++ct)
            acc[rt][ct] = (floatx4){0.f, 0.f, 0.f, 0.f};

    const int rowb = rowhalf * 64 + li;
    const char* ybase[4];
    const char* xbase[4];
#pragma unroll
    for (int rt = 0; rt < 4; ++rt) {
        int row = rowb + rt * 16;
        ybase[rt] = (const char*)ylds + row * (YSTR * 2) + kg * 16;
        xbase[rt] = (const char*)xlds + row * (XSTR * 2);
    }
    const bool w1 = kg >= 1, w2 = kg >= 2, w3 = kg >= 3;

    // per-lane B-frag offset inside a chunk (swizzled slots, bank-uniform)
    const int bfoff = (obase + li) * 64 + ((kg ^ ((li >> 1) & 3)) * 16);

    // phase tables, period 5 (k-step advances 32; 5*32 = 4*40)
    // yimm: byte offset of (32p mod 40); wrap-kind: which kg-threshold wraps
    const int R32[5] = {0, 64, 48, 32, 16};
    const int B5[5]  = {0, 0, 1, 2, 3};
    const int WK[5]  = {0, 1, 2, 3, 0};

    for (int g = 0; g < 5; ++g) {
        // x window for this group: elements 8g..8g+7 per row, pre-dup'd
        half2v xd[4][8];
#pragma unroll
        for (int rt = 0; rt < 4; ++rt) {
            half8 xq = *(const half8*)(xbase[rt] + g * 16);
#pragma unroll
            for (int e = 0; e < 8; ++e)
                xd[rt][e] = (half2v){xq[e], xq[e]};
        }

#pragma unroll
        for (int ss = 0; ss < 5; ++ss) {
            const int sstep = g * 5 + ss;
            if (sstep + 1 < NSUPER) {
                const char* src = (const char*)Wh + (size_t)(sstep + 1) * SUPER_BYTES;
                unsigned char* dst = bsm + ((sstep + 1) & 1) * SUPER_BYTES;
                for (int c = wave; c < 26; c += 4) {
                    int off = c * 1024 + lane * 16;
                    __builtin_amdgcn_global_load_lds(
                        (const __attribute__((address_space(1))) unsigned int*)(src + off),
                        (__attribute__((address_space(3))) unsigned int*)(dst + off),
                        16, 0, 0);
                }
            }
            const unsigned char* cbuf = bsm + (sstep & 1) * SUPER_BYTES;

#pragma unroll
            for (int half = 0; half < 2; ++half) {
                const int p  = 2 * ss + half;          // phase 0..9, compile-time
                const int pm = p % 5, pd = p / 5;
                const int yimm  = R32[pm];
                const int dbase = B5[pm] + 4 * pd;
                const int wk    = WK[pm];
                const bool use  = (wk == 1) ? w1 : (wk == 2) ? w2 : (wk == 3) ? w3 : false;
                const unsigned char* chunk = cbuf + half * CHUNK_BYTES;

                half8 bf[7];
#pragma unroll
                for (int ct = 0; ct < 7; ++ct)
                    if (ct < ntiles)
                        bf[ct] = *(const half8*)(chunk + bfoff + ct * 1024);

                half8 af[4];
#pragma unroll
                for (int rt = 0; rt < 4; ++rt) {
                    const char* ya = ybase[rt] + (yimm - (use ? 80 : 0));
                    half8 yv = *(const half8*)ya;
                    half2v xs = use ? xd[rt][dbase + 1] : xd[rt][dbase];
                    half8 xsp = __builtin_shufflevector(xs, xs, 0, 1, 0, 1, 0, 1, 0, 1);
                    af[rt] = xsp * yv;
                }

#pragma unroll
                for (int ct = 0; ct < 7; ++ct)
                    if (ct < ntiles)
#pragma unroll
                        for (int rt = 0; rt < 4; ++rt)
                            acc[rt][ct] = __builtin_amdgcn_mfma_f32_16x16x32_f16(
                                af[rt], bf[ct], acc[rt][ct], 0, 0, 0);
            }
            __syncthreads();   // one drain per super-step (25 total)
        }
    }

    // ---- epilogue: C/D layout col = lane&15, row = (lane>>4)*4 + reg  [m89]
#pragma unroll
    for (int rt = 0; rt < 4; ++rt) {
#pragma unroll
        for (int ct = 0; ct < 7; ++ct) {
            if (ct >= ntiles) continue;
            int gcol = obase + ct * 16 + li;
            if (gcol < OOv) {
#pragma unroll
                for (int r4 = 0; r4 < 4; ++r4) {
                    long grow = blockbase + rowhalf * 64 + rt * 16 + kg * 4 + r4;
                    Out[grow * OOv + gcol] = acc[rt][ct][r4];
                }
            }
        }
    }
}

extern "C" void kernel_launch(void* const* d_in, const int* in_sizes, int n_in,
                              void* d_out, int out_size, void* d_ws, size_t ws_size,
                              hipStream_t stream) {
    (void)in_sizes; (void)n_in; (void)out_size; (void)ws_size;
    const float* X = (const float*)d_in[0];
    const float* Y = (const float*)d_in[1];
    const float* W = (const float*)d_in[2];
    float* Out = (float*)d_out;
    unsigned short* Wh = (unsigned short*)d_ws;   // 665,600 B scratch

    wb_convert_kernel<<<1300, 256, 0, stream>>>(W, Wh);
    cin_mfma_kernel<<<512, 256, 0, stream>>>(X, Y, Wh, Out);
}